// Round 1
// baseline (555.356 us; speedup 1.0000x reference)
//
#include <hip/hip_runtime.h>
#include <math.h>

// Problem dims
#define Mm 8
#define Bb 64
#define Ss 1024
#define Kk 256
#define Hh 8
#define HD 32
#define Ff 1024

// Workspace layout (float offsets). Overlapping regions have disjoint lifetimes:
//   Q [0,131072)            K1 -> K2      (later reused as FC)
//   U [131072, 1179648)     K2 -> K3      (later reused: GATES at 262144)
//   QDB [1179648, 1183744)  K2 -> K3
//   SC [1183744, 5378048)   K3 -> K4a     (later reused as HPART)
//   WPART [5378048, 9572352) K4a -> K4b   (later reused as H1)
//   W [9572352, 10620928)   K4b -> K5
#define WS_Q      0u
#define WS_U      131072u
#define WS_QDB    1179648u
#define WS_SC     1183744u
#define WS_WPART  5378048u
#define WS_W      9572352u
#define WS_FC     0u         // overlays Q (dead after K2)
#define WS_H1     5378048u   // overlays WPART (dead after K4b)
#define WS_GATES  262144u    // overlays U (dead after K3)
#define WS_HPART  1183744u   // overlays SC (dead after K4a)
// total required: 10620928 floats = 42.5 MB

// ---------------------------------------------------------------------------
// K1: q = q0 @ Wq + bq        (M,B,K)
// grid (8, 8) : (m, b-tile of 8), 256 threads (thread = output column d)
__global__ __launch_bounds__(256) void k1_qproj(
    const float* __restrict__ q0, const float* __restrict__ wq,
    const float* __restrict__ bq, float* __restrict__ qout) {
  __shared__ float q0s[8 * 260];
  const int m = blockIdx.x, b0 = blockIdx.y * 8, t = threadIdx.x;
#pragma unroll
  for (int j = 0; j < 8; ++j)
    q0s[j * 260 + t] = q0[(m * Bb + b0 + j) * Kk + t];
  __syncthreads();
  float acc[8];
  const float bias = bq[m * Kk + t];
#pragma unroll
  for (int j = 0; j < 8; ++j) acc[j] = bias;
  const float* wcol = wq + m * Kk * Kk + t;
  for (int k4 = 0; k4 < Kk / 4; ++k4) {
    const float w0 = wcol[(k4 * 4 + 0) * Kk];
    const float w1 = wcol[(k4 * 4 + 1) * Kk];
    const float w2 = wcol[(k4 * 4 + 2) * Kk];
    const float w3 = wcol[(k4 * 4 + 3) * Kk];
#pragma unroll
    for (int j = 0; j < 8; ++j) {
      const float4 qv = *(const float4*)&q0s[j * 260 + k4 * 4];
      acc[j] += qv.x * w0 + qv.y * w1 + qv.z * w2 + qv.w * w3;
    }
  }
#pragma unroll
  for (int j = 0; j < 8; ++j)
    qout[(m * Bb + b0 + j) * Kk + t] = acc[j];
}

// ---------------------------------------------------------------------------
// K2: u(m,b,h,k) = sum_d Wk[m,k,h*32+d] * q[m,b,h*32+d]
//     qdb(m,b,h) = sum_d q[m,b,h*32+d] * bk[m,h*32+d]
// grid (8, 8) : (m, h), 256 threads (thread = k row of Wk)
__global__ __launch_bounds__(256) void k2_uproj(
    const float* __restrict__ wk, const float* __restrict__ bk,
    const float* __restrict__ q, float* __restrict__ u,
    float* __restrict__ qdb) {
  __shared__ float qs[64 * 36];
  const int m = blockIdx.x, h = blockIdx.y, t = threadIdx.x;
#pragma unroll
  for (int p = 0; p < 8; ++p) {
    const int idx = p * 256 + t;
    const int d = idx & 31, b = idx >> 5;
    qs[b * 36 + d] = q[(m * Bb + b) * Kk + h * HD + d];
  }
  __syncthreads();
  float acc[64];
#pragma unroll
  for (int b = 0; b < 64; ++b) acc[b] = 0.f;
  const float* wrow = wk + (m * Kk + t) * Kk + h * HD;  // 32 contiguous floats
#pragma unroll
  for (int d4 = 0; d4 < 8; ++d4) {
    const float4 w4 = *(const float4*)&wrow[d4 * 4];
#pragma unroll
    for (int b = 0; b < 64; ++b) {
      const float4 q4 = *(const float4*)&qs[b * 36 + d4 * 4];
      acc[b] += q4.x * w4.x + q4.y * w4.y + q4.z * w4.z + q4.w * w4.w;
    }
  }
  for (int b = 0; b < 64; ++b)
    u[((m * Bb + b) * Hh + h) * Kk + t] = acc[b];
  if (t < 64) {
    float s = 0.f;
#pragma unroll
    for (int d = 0; d < 32; ++d)
      s += qs[t * 36 + d] * bk[m * Kk + h * HD + d];
    qdb[(m * Bb + t) * Hh + h] = s;
  }
}

// ---------------------------------------------------------------------------
// K3: raw scores(m,b,h,s) = (key(s,b,:)·u(m,b,h,:) + qdb)/sqrt(32)
// grid (64, 2, 32) : (b, mh-half of 32, s-chunk of 32), 256 threads
// thread computes 2 mh-rows {tmh, tmh+16} x 2 s {2ts, 2ts+1}
__global__ __launch_bounds__(256) void k3_scores(
    const float* __restrict__ key, const float* __restrict__ u,
    const float* __restrict__ qdb, float* __restrict__ sc) {
  __shared__ float us[32 * 260];
  __shared__ float kt[32 * 132];
  __shared__ float qd[32];
  const int b = blockIdx.x, mhh = blockIdx.y, s0 = blockIdx.z * 32,
            t = threadIdx.x;
  for (int p = 0; p < 32; ++p) {
    const int mh = mhh * 32 + p;
    us[p * 260 + t] = u[(((mh >> 3) * Bb + b) * Hh + (mh & 7)) * Kk + t];
  }
  if (t < 32) {
    const int mh = mhh * 32 + t;
    qd[t] = qdb[((mh >> 3) * Bb + b) * Hh + (mh & 7)];
  }
  float acc00 = 0.f, acc01 = 0.f, acc10 = 0.f, acc11 = 0.f;
  const int tmh = t & 15, ts = t >> 4;
  for (int kh = 0; kh < 2; ++kh) {
    __syncthreads();
#pragma unroll
    for (int p = 0; p < 16; ++p) {
      const int idx = p * 256 + t;
      const int k = idx & 127, sl = idx >> 7;
      kt[sl * 132 + k] = key[(s0 + sl) * (Bb * Kk) + b * Kk + kh * 128 + k];
    }
    __syncthreads();
#pragma unroll 8
    for (int k4 = 0; k4 < 32; ++k4) {
      const float4 u0 = *(const float4*)&us[tmh * 260 + kh * 128 + k4 * 4];
      const float4 u1 = *(const float4*)&us[(tmh + 16) * 260 + kh * 128 + k4 * 4];
      const float4 c0 = *(const float4*)&kt[(2 * ts) * 132 + k4 * 4];
      const float4 c1 = *(const float4*)&kt[(2 * ts + 1) * 132 + k4 * 4];
      acc00 += u0.x * c0.x + u0.y * c0.y + u0.z * c0.z + u0.w * c0.w;
      acc01 += u0.x * c1.x + u0.y * c1.y + u0.z * c1.z + u0.w * c1.w;
      acc10 += u1.x * c0.x + u1.y * c0.y + u1.z * c0.z + u1.w * c0.w;
      acc11 += u1.x * c1.x + u1.y * c1.y + u1.z * c1.z + u1.w * c1.w;
    }
  }
  const float scale = 0.17677669529663687f;  // 1/sqrt(32)
  const int mh0 = mhh * 32 + tmh, mh1 = mh0 + 16;
  const int r0 = ((mh0 >> 3) * Bb + b) * Hh + (mh0 & 7);
  const int r1 = ((mh1 >> 3) * Bb + b) * Hh + (mh1 & 7);
  const int s = s0 + 2 * ts;
  sc[r0 * Ss + s]     = (acc00 + qd[tmh]) * scale;
  sc[r0 * Ss + s + 1] = (acc01 + qd[tmh]) * scale;
  sc[r1 * Ss + s]     = (acc10 + qd[tmh + 16]) * scale;
  sc[r1 * Ss + s + 1] = (acc11 + qd[tmh + 16]) * scale;
}

// ---------------------------------------------------------------------------
// K3b: in-place softmax over s (per m,b,h) + attn_weights = mean over h
// grid (8, 64) : (m, b), 256 threads
__global__ __launch_bounds__(256) void k3b_softmax(float* __restrict__ sc,
                                                   float* __restrict__ out) {
  __shared__ float rows[8 * 1024];
  __shared__ float red[8];
  const int m = blockIdx.x, b = blockIdx.y, t = threadIdx.x;
  const int base = (m * Bb + b) * (Hh * Ss);
  for (int p = 0; p < 32; ++p)
    rows[p * 256 + t] = sc[base + p * 256 + t];
  __syncthreads();
  const int lane = t & 63, wid = t >> 6;
  for (int h = 0; h < 8; ++h) {
    float v0 = rows[h * 1024 + t], v1 = rows[h * 1024 + 256 + t],
          v2 = rows[h * 1024 + 512 + t], v3 = rows[h * 1024 + 768 + t];
    float mx = fmaxf(fmaxf(v0, v1), fmaxf(v2, v3));
    for (int off = 32; off > 0; off >>= 1)
      mx = fmaxf(mx, __shfl_down(mx, off, 64));
    if (lane == 0) red[wid] = mx;
    __syncthreads();
    mx = fmaxf(fmaxf(red[0], red[1]), fmaxf(red[2], red[3]));
    v0 = __expf(v0 - mx); v1 = __expf(v1 - mx);
    v2 = __expf(v2 - mx); v3 = __expf(v3 - mx);
    float sm = v0 + v1 + v2 + v3;
    for (int off = 32; off > 0; off >>= 1) sm += __shfl_down(sm, off, 64);
    if (lane == 0) red[4 + wid] = sm;
    __syncthreads();
    const float inv = 1.f / (red[4] + red[5] + red[6] + red[7]);
    v0 *= inv; v1 *= inv; v2 *= inv; v3 *= inv;
    rows[h * 1024 + t] = v0; rows[h * 1024 + 256 + t] = v1;
    rows[h * 1024 + 512 + t] = v2; rows[h * 1024 + 768 + t] = v3;
    sc[base + h * 1024 + t] = v0; sc[base + h * 1024 + 256 + t] = v1;
    sc[base + h * 1024 + 512 + t] = v2; sc[base + h * 1024 + 768 + t] = v3;
    __syncthreads();
  }
#pragma unroll
  for (int i = 0; i < 4; ++i) {
    const int s = i * 256 + t;
    float sum = 0.f;
#pragma unroll
    for (int h = 0; h < 8; ++h) sum += rows[h * 1024 + s];
    out[131072u + (m * Bb + b) * Ss + s] = sum * 0.125f;
  }
}

// ---------------------------------------------------------------------------
// K4a: partial w(m,b,h,k) = sum_{s in chunk} aw(m,b,h,s)*value(s,b,k)
// grid (64, 4) : (b, s-chunk of 256), 256 threads, 8x8 register tile
__global__ __launch_bounds__(256) void k4a_av(const float* __restrict__ value,
                                              const float* __restrict__ aw,
                                              float* __restrict__ wpart) {
  __shared__ float aws[64 * 36];
  __shared__ float vs[32 * 260];
  const int b = blockIdx.x, sc4 = blockIdx.y, t = threadIdx.x;
  const int tmh = t & 7, tk = t >> 3;  // tk in 0..31
  float acc[8][8];
#pragma unroll
  for (int a = 0; a < 8; ++a)
#pragma unroll
    for (int j = 0; j < 8; ++j) acc[a][j] = 0.f;
  for (int st = 0; st < 8; ++st) {
    __syncthreads();
    const int s0 = sc4 * 256 + st * 32;
#pragma unroll
    for (int p = 0; p < 8; ++p) {
      const int idx = p * 256 + t;
      const int s = idx & 31, j = idx >> 5;
      aws[j * 36 + s] =
          aw[(((j >> 3) * Bb + b) * Hh + (j & 7)) * Ss + s0 + s];
    }
#pragma unroll
    for (int p = 0; p < 32; ++p)
      vs[p * 260 + t] = value[(s0 + p) * (Bb * Kk) + b * Kk + t];
    __syncthreads();
#pragma unroll 2
    for (int s4 = 0; s4 < 8; ++s4) {
      float4 av[8];
#pragma unroll
      for (int a = 0; a < 8; ++a)
        av[a] = *(const float4*)&aws[(tmh + 8 * a) * 36 + s4 * 4];
#pragma unroll
      for (int ss = 0; ss < 4; ++ss) {
        const float4 v0 = *(const float4*)&vs[(s4 * 4 + ss) * 260 + tk * 4];
        const float4 v1 =
            *(const float4*)&vs[(s4 * 4 + ss) * 260 + 128 + tk * 4];
#pragma unroll
        for (int a = 0; a < 8; ++a) {
          const float aval = (ss == 0) ? av[a].x
                             : (ss == 1) ? av[a].y
                             : (ss == 2) ? av[a].z : av[a].w;
          acc[a][0] += aval * v0.x; acc[a][1] += aval * v0.y;
          acc[a][2] += aval * v0.z; acc[a][3] += aval * v0.w;
          acc[a][4] += aval * v1.x; acc[a][5] += aval * v1.y;
          acc[a][6] += aval * v1.z; acc[a][7] += aval * v1.w;
        }
      }
    }
  }
  float* wp = wpart + sc4 * 1048576u;
#pragma unroll
  for (int a = 0; a < 8; ++a) {
    const int mh = tmh + 8 * a;
    const int rb = (((mh >> 3) * Bb + b) * Hh + (mh & 7)) * Kk;
    float4 r0 = {acc[a][0], acc[a][1], acc[a][2], acc[a][3]};
    float4 r1 = {acc[a][4], acc[a][5], acc[a][6], acc[a][7]};
    *(float4*)&wp[rb + tk * 4] = r0;
    *(float4*)&wp[rb + 128 + tk * 4] = r1;
  }
}

// K4b: w = sum of 4 partials. grid 1024, 256 threads, float4 each
__global__ __launch_bounds__(256) void k4b_reduce(
    const float* __restrict__ wpart, float* __restrict__ w) {
  const int i = (blockIdx.x * 256 + threadIdx.x) * 4;
  const float4 a = *(const float4*)&wpart[i];
  const float4 c = *(const float4*)&wpart[1048576u + i];
  const float4 d = *(const float4*)&wpart[2097152u + i];
  const float4 e = *(const float4*)&wpart[3145728u + i];
  float4 r;
  r.x = a.x + c.x + d.x + e.x; r.y = a.y + c.y + d.y + e.y;
  r.z = a.z + c.z + d.z + e.z; r.w = a.w + c.w + d.w + e.w;
  *(float4*)&w[i] = r;
}

// ---------------------------------------------------------------------------
// K5: ctx = w @ Wv_h + bv ; attn_out = ctx @ Wo + bo ; fc_in = relu(concat)
// grid (8, 64) : (m, b), 256 threads (thread = output column)
__global__ __launch_bounds__(256) void k5_ctx(
    const float* __restrict__ wv, const float* __restrict__ bv,
    const float* __restrict__ wo, const float* __restrict__ bo,
    const float* __restrict__ s0in, const float* __restrict__ w,
    float* __restrict__ attn_out, float* __restrict__ fc) {
  __shared__ float wsh[2048];
  __shared__ float ctxs[256];
  const int m = blockIdx.x, b = blockIdx.y, t = threadIdx.x;
  const int base = (m * Bb + b) * (Hh * Kk);
#pragma unroll
  for (int p = 0; p < 8; ++p) wsh[p * 256 + t] = w[base + p * 256 + t];
  __syncthreads();
  const int h = t >> 5;  // column t = h*32 + d
  float acc = bv[m * Kk + t];
  const float* wvc = wv + m * Kk * Kk + t;
  for (int k4 = 0; k4 < 64; ++k4) {
    const float4 a4 = *(const float4*)&wsh[h * 256 + k4 * 4];
    acc += a4.x * wvc[(k4 * 4 + 0) * Kk] + a4.y * wvc[(k4 * 4 + 1) * Kk] +
           a4.z * wvc[(k4 * 4 + 2) * Kk] + a4.w * wvc[(k4 * 4 + 3) * Kk];
  }
  ctxs[t] = acc;
  __syncthreads();
  float acc2 = bo[m * Kk + t];
  const float* woc = wo + m * Kk * Kk + t;
  for (int k4 = 0; k4 < 64; ++k4) {
    const float4 c4 = *(const float4*)&ctxs[k4 * 4];
    acc2 += c4.x * woc[(k4 * 4 + 0) * Kk] + c4.y * woc[(k4 * 4 + 1) * Kk] +
            c4.z * woc[(k4 * 4 + 2) * Kk] + c4.w * woc[(k4 * 4 + 3) * Kk];
  }
  const int ob = (m * Bb + b) * Kk + t;
  attn_out[ob] = acc2;
  fc[(m * Bb + b) * 512 + t] = fmaxf(acc2, 0.f);
  fc[(m * Bb + b) * 512 + 256 + t] = fmaxf(s0in[ob], 0.f);
}

// ---------------------------------------------------------------------------
// K6: h1[head] = relu(fc_in @ W1[head] + b1[head]), heads 0..3 = q,k,v,s; 4..7 = gates
// grid (4, 8, 8) : (f-tile of 256, m, head), 256 threads, 8x8 register tile
__global__ __launch_bounds__(256) void k6_mlp1(
    const float* __restrict__ fc, const float* __restrict__ w1q,
    const float* __restrict__ w1k, const float* __restrict__ w1v,
    const float* __restrict__ w1s, const float* __restrict__ w1g,
    const float* __restrict__ b1q, const float* __restrict__ b1k,
    const float* __restrict__ b1v, const float* __restrict__ b1s,
    const float* __restrict__ b1g, float* __restrict__ h1) {
  __shared__ float At[32 * 68];   // transposed fc tile [i][b]
  __shared__ float Wt[32 * 260];  // weight tile [i][f 0..255]
  const int ft = blockIdx.x, m = blockIdx.y, head = blockIdx.z,
            t = threadIdx.x;
  const float* w1;
  const float* b1;
  if (head == 0)      { w1 = w1q; b1 = b1q; }
  else if (head == 1) { w1 = w1k; b1 = b1k; }
  else if (head == 2) { w1 = w1v; b1 = b1v; }
  else if (head == 3) { w1 = w1s; b1 = b1s; }
  else {
    w1 = w1g + (head - 4) * (Mm * 512 * Ff);
    b1 = b1g + (head - 4) * (Mm * Ff);
  }
  w1 += m * 512 * Ff;
  b1 += m * Ff;
  const int tf = t & 31, tb = t >> 5;  // thread: 8 b rows, f cols {4tf..,128+4tf..}
  float acc[8][8];
#pragma unroll
  for (int i = 0; i < 8; ++i)
#pragma unroll
    for (int j = 0; j < 8; ++j) acc[i][j] = 0.f;
  for (int it = 0; it < 16; ++it) {
    __syncthreads();
#pragma unroll
    for (int p = 0; p < 8; ++p) {
      const int idx = p * 256 + t;
      const int i = idx & 31, bb = idx >> 5;
      At[i * 68 + bb] = fc[(m * Bb + bb) * 512 + it * 32 + i];
    }
#pragma unroll
    for (int p = 0; p < 32; ++p)
      Wt[p * 260 + t] = w1[(it * 32 + p) * Ff + ft * 256 + t];
    __syncthreads();
#pragma unroll 4
    for (int kk = 0; kk < 32; ++kk) {
      const float4 a0 = *(const float4*)&At[kk * 68 + tb * 8];
      const float4 a1 = *(const float4*)&At[kk * 68 + tb * 8 + 4];
      const float4 w0 = *(const float4*)&Wt[kk * 260 + tf * 4];
      const float4 w1r = *(const float4*)&Wt[kk * 260 + 128 + tf * 4];
      const float av[8] = {a0.x, a0.y, a0.z, a0.w, a1.x, a1.y, a1.z, a1.w};
#pragma unroll
      for (int i = 0; i < 8; ++i) {
        acc[i][0] += av[i] * w0.x; acc[i][1] += av[i] * w0.y;
        acc[i][2] += av[i] * w0.z; acc[i][3] += av[i] * w0.w;
        acc[i][4] += av[i] * w1r.x; acc[i][5] += av[i] * w1r.y;
        acc[i][6] += av[i] * w1r.z; acc[i][7] += av[i] * w1r.w;
      }
    }
  }
  const float4 bv0 = *(const float4*)&b1[ft * 256 + tf * 4];
  const float4 bv1 = *(const float4*)&b1[ft * 256 + 128 + tf * 4];
  float* hb = h1 + (size_t)((head * Mm + m) * Bb) * Ff + ft * 256;
#pragma unroll
  for (int i = 0; i < 8; ++i) {
    const int bb = tb * 8 + i;
    float4 r0, r1;
    r0.x = fmaxf(acc[i][0] + bv0.x, 0.f);
    r0.y = fmaxf(acc[i][1] + bv0.y, 0.f);
    r0.z = fmaxf(acc[i][2] + bv0.z, 0.f);
    r0.w = fmaxf(acc[i][3] + bv0.w, 0.f);
    r1.x = fmaxf(acc[i][4] + bv1.x, 0.f);
    r1.y = fmaxf(acc[i][5] + bv1.y, 0.f);
    r1.z = fmaxf(acc[i][6] + bv1.z, 0.f);
    r1.w = fmaxf(acc[i][7] + bv1.w, 0.f);
    *(float4*)&hb[bb * Ff + tf * 4] = r0;
    *(float4*)&hb[bb * Ff + 128 + tf * 4] = r1;
  }
}

// ---------------------------------------------------------------------------
// K6b: gates(g,m,b) = sigmoid(h1[4+g,m,b,:] . g_w2[g,m,:] + g_b2[g,m])
// grid (32, 64) : (g*8+m, b), 64 threads
__global__ __launch_bounds__(64) void k6b_gates(
    const float* __restrict__ h1, const float* __restrict__ gw2,
    const float* __restrict__ gb2, float* __restrict__ gates) {
  const int gm = blockIdx.x, b = blockIdx.y, t = threadIdx.x;
  const int g = gm >> 3, m = gm & 7;
  const float* hrow = h1 + (size_t)(((4 + g) * Mm + m) * Bb + b) * Ff;
  const float* wrow = gw2 + (g * Mm + m) * Ff;
  float s = 0.f;
#pragma unroll
  for (int i = 0; i < 16; ++i) s += hrow[t + i * 64] * wrow[t + i * 64];
  for (int off = 32; off > 0; off >>= 1) s += __shfl_down(s, off, 64);
  if (t == 0)
    gates[(g * Mm + m) * Bb + b] =
        1.f / (1.f + __expf(-(s + gb2[g * Mm + m])));
}

// ---------------------------------------------------------------------------
// K7a: partial second-layer head outputs over an f-half
// grid (8, 8, 4) : (oc*2+fh, m, head), 256 threads, 4x4 register tile
__global__ __launch_bounds__(256) void k7a_mlp2(
    const float* __restrict__ h1, const float* __restrict__ w2q,
    const float* __restrict__ w2k, const float* __restrict__ w2v,
    const float* __restrict__ w2s, float* __restrict__ hpart) {
  __shared__ float Ht[32 * 68];
  __shared__ float Wt[32 * 68];
  const int oc = blockIdx.x >> 1, fh = blockIdx.x & 1;
  const int m = blockIdx.y, head = blockIdx.z, t = threadIdx.x;
  const float* w2 =
      (head == 0) ? w2q : (head == 1) ? w2k : (head == 2) ? w2v : w2s;
  w2 += (size_t)m * Ff * Kk;
  const float* hbase = h1 + (size_t)((head * Mm + m) * Bb) * Ff + fh * 512;
  const int to = t & 15, tb = t >> 4;
  float acc[4][4];
#pragma unroll
  for (int j = 0; j < 4; ++j)
#pragma unroll
    for (int i = 0; i < 4; ++i) acc[j][i] = 0.f;
  for (int it = 0; it < 16; ++it) {
    __syncthreads();
#pragma unroll
    for (int p = 0; p < 8; ++p) {
      const int idx = p * 256 + t;
      const int f = idx & 31, bb = idx >> 5;
      Ht[f * 68 + bb] = hbase[bb * Ff + it * 32 + f];
    }
#pragma unroll
    for (int p = 0; p < 8; ++p) {
      const int idx = p * 256 + t;
      const int o = idx & 63, f = idx >> 6;
      Wt[f * 68 + o] = w2[(fh * 512 + it * 32 + f) * Kk + oc * 64 + o];
    }
    __syncthreads();
#pragma unroll 8
    for (int kk = 0; kk < 32; ++kk) {
      const float4 a4 = *(const float4*)&Ht[kk * 68 + tb * 4];
      const float4 w4 = *(const float4*)&Wt[kk * 68 + to * 4];
      acc[0][0] += a4.x * w4.x; acc[0][1] += a4.x * w4.y;
      acc[0][2] += a4.x * w4.z; acc[0][3] += a4.x * w4.w;
      acc[1][0] += a4.y * w4.x; acc[1][1] += a4.y * w4.y;
      acc[1][2] += a4.y * w4.z; acc[1][3] += a4.y * w4.w;
      acc[2][0] += a4.z * w4.x; acc[2][1] += a4.z * w4.y;
      acc[2][2] += a4.z * w4.z; acc[2][3] += a4.z * w4.w;
      acc[3][0] += a4.w * w4.x; acc[3][1] += a4.w * w4.y;
      acc[3][2] += a4.w * w4.z; acc[3][3] += a4.w * w4.w;
    }
  }
  float* hp = hpart + (size_t)(((fh * 4 + head) * Mm + m) * Bb) * Kk + oc * 64;
#pragma unroll
  for (int j = 0; j < 4; ++j) {
    const int bb = tb * 4 + j;
    float4 r = {acc[j][0], acc[j][1], acc[j][2], acc[j][3]};
    *(float4*)&hp[bb * Kk + to * 4] = r;
  }
}

// ---------------------------------------------------------------------------
// K7b: out = gate*tanh(relu(p0+p1+b2)) + (1-gate)*x0, scatter to d_out
// grid 2048, 256 threads
__global__ __launch_bounds__(256) void k7b_final(
    const float* __restrict__ hpart, const float* __restrict__ gates,
    const float* __restrict__ b2q, const float* __restrict__ b2k,
    const float* __restrict__ b2v, const float* __restrict__ b2s,
    const float* __restrict__ q0, const float* __restrict__ k0,
    const float* __restrict__ v0, const float* __restrict__ s0,
    float* __restrict__ out) {
  const int idx = blockIdx.x * 256 + threadIdx.x;  // 0..524287
  const int o = idx & 255;
  const int b = (idx >> 8) & 63;
  const int m = (idx >> 14) & 7;
  const int head = idx >> 17;
  const float* b2 = (head == 0) ? b2q : (head == 1) ? b2k
                    : (head == 2) ? b2v : b2s;
  const float* x0 = (head == 0) ? q0 : (head == 1) ? k0
                    : (head == 2) ? v0 : s0;
  const unsigned ooff = (head == 0) ? 786432u
                        : (head == 1) ? 917504u
                        : (head == 2) ? 1048576u : 655360u;
  float v = hpart[idx] + hpart[524288u + idx] + b2[m * Kk + o];
  v = tanhf(fmaxf(v, 0.f));
  const float g = gates[(head * Mm + m) * Bb + b];
  const float x = x0[(m * Bb + b) * Kk + o];
  out[ooff + (m * Bb + b) * Kk + o] = g * v + (1.f - g) * x;
}

// ---------------------------------------------------------------------------
extern "C" void kernel_launch(void* const* d_in, const int* in_sizes, int n_in,
                              void* d_out, int out_size, void* d_ws,
                              size_t ws_size, hipStream_t stream) {
  (void)in_sizes; (void)n_in; (void)out_size; (void)ws_size;
  const float* s0  = (const float*)d_in[0];
  const float* q0  = (const float*)d_in[1];
  const float* k0  = (const float*)d_in[2];
  const float* v0  = (const float*)d_in[3];
  const float* key = (const float*)d_in[4];
  const float* val = (const float*)d_in[5];
  const float* wq  = (const float*)d_in[6];
  const float* wk  = (const float*)d_in[7];
  const float* wv  = (const float*)d_in[8];
  const float* bqa = (const float*)d_in[9];
  const float* bka = (const float*)d_in[10];
  const float* bva = (const float*)d_in[11];
  const float* wo  = (const float*)d_in[12];
  const float* bo  = (const float*)d_in[13];
  const float* qw1 = (const float*)d_in[14];
  const float* qb1 = (const float*)d_in[15];
  const float* qw2 = (const float*)d_in[16];
  const float* qb2 = (const float*)d_in[17];
  const float* kw1 = (const float*)d_in[18];
  const float* kb1 = (const float*)d_in[19];
  const float* kw2 = (const float*)d_in[20];
  const float* kb2 = (const float*)d_in[21];
  const float* vw1 = (const float*)d_in[22];
  const float* vb1 = (const float*)d_in[23];
  const float* vw2 = (const float*)d_in[24];
  const float* vb2 = (const float*)d_in[25];
  const float* sw1 = (const float*)d_in[26];
  const float* sb1 = (const float*)d_in[27];
  const float* sw2 = (const float*)d_in[28];
  const float* sb2 = (const float*)d_in[29];
  const float* gw1 = (const float*)d_in[30];
  const float* gb1 = (const float*)d_in[31];
  const float* gw2 = (const float*)d_in[32];
  const float* gb2 = (const float*)d_in[33];
  float* ws  = (float*)d_ws;
  float* out = (float*)d_out;

  k1_qproj<<<dim3(8, 8), 256, 0, stream>>>(q0, wq, bqa, ws + WS_Q);
  k2_uproj<<<dim3(8, 8), 256, 0, stream>>>(wk, bka, ws + WS_Q, ws + WS_U,
                                           ws + WS_QDB);
  k3_scores<<<dim3(64, 2, 32), 256, 0, stream>>>(key, ws + WS_U, ws + WS_QDB,
                                                 ws + WS_SC);
  k3b_softmax<<<dim3(8, 64), 256, 0, stream>>>(ws + WS_SC, out);
  k4a_av<<<dim3(64, 4), 256, 0, stream>>>(val, ws + WS_SC, ws + WS_WPART);
  k4b_reduce<<<dim3(1024), 256, 0, stream>>>(ws + WS_WPART, ws + WS_W);
  k5_ctx<<<dim3(8, 64), 256, 0, stream>>>(wv, bva, wo, bo, s0, ws + WS_W, out,
                                          ws + WS_FC);
  k6_mlp1<<<dim3(4, 8, 8), 256, 0, stream>>>(ws + WS_FC, qw1, kw1, vw1, sw1,
                                             gw1, qb1, kb1, vb1, sb1, gb1,
                                             ws + WS_H1);
  k6b_gates<<<dim3(32, 64), 64, 0, stream>>>(ws + WS_H1, gw2, gb2,
                                             ws + WS_GATES);
  k7a_mlp2<<<dim3(8, 8, 4), 256, 0, stream>>>(ws + WS_H1, qw2, kw2, vw2, sw2,
                                              ws + WS_HPART);
  k7b_final<<<dim3(2048), 256, 0, stream>>>(ws + WS_HPART, ws + WS_GATES, qb2,
                                            kb2, vb2, sb2, q0, k0, v0, s0,
                                            out);
}

// Round 2
// 524.495 us; speedup vs baseline: 1.0588x; 1.0588x over previous
//
#include <hip/hip_runtime.h>
#include <math.h>

// Problem dims
#define Mm 8
#define Bb 64
#define Ss 1024
#define Kk 256
#define Hh 8
#define HD 32
#define Ff 1024

// Workspace layout (float offsets). Overlapping regions have disjoint lifetimes:
//   Q [0,131072)            K1 -> K2      (later reused as FC)
//   U [131072, 1179648)     K2 -> K3      (later reused: GATES at 262144)
//   QDB [1179648, 1183744)  K2 -> K3
//   SC [1183744, 5378048)   K3 -> K4a     (later reused as HPART, 4 partials)
//   WPART [5378048, 9572352) K4a -> K5 (4 partials; later reused as H1)
#define WS_Q      0u
#define WS_U      131072u
#define WS_QDB    1179648u
#define WS_SC     1183744u
#define WS_WPART  5378048u
#define WS_FC     0u         // overlays Q (dead after K2)
#define WS_H1     5378048u   // overlays WPART (dead after K5)
#define WS_GATES  262144u    // overlays U (dead after K3)
#define WS_HPART  1183744u   // overlays SC (dead after K4a); 4x524288 floats
// total required: 9572352 floats = 38.3 MB

// ---------------------------------------------------------------------------
// K1: q = q0 @ Wq + bq        (M,B,K)
// grid (8, 8) : (m, b-tile of 8), 256 threads (thread = output column d)
__global__ __launch_bounds__(256) void k1_qproj(
    const float* __restrict__ q0, const float* __restrict__ wq,
    const float* __restrict__ bq, float* __restrict__ qout) {
  __shared__ float q0s[8 * 260];
  const int m = blockIdx.x, b0 = blockIdx.y * 8, t = threadIdx.x;
#pragma unroll
  for (int j = 0; j < 8; ++j)
    q0s[j * 260 + t] = q0[(m * Bb + b0 + j) * Kk + t];
  __syncthreads();
  float acc[8];
  const float bias = bq[m * Kk + t];
#pragma unroll
  for (int j = 0; j < 8; ++j) acc[j] = bias;
  const float* wcol = wq + m * Kk * Kk + t;
  for (int k4 = 0; k4 < Kk / 4; ++k4) {
    const float w0 = wcol[(k4 * 4 + 0) * Kk];
    const float w1 = wcol[(k4 * 4 + 1) * Kk];
    const float w2 = wcol[(k4 * 4 + 2) * Kk];
    const float w3 = wcol[(k4 * 4 + 3) * Kk];
#pragma unroll
    for (int j = 0; j < 8; ++j) {
      const float4 qv = *(const float4*)&q0s[j * 260 + k4 * 4];
      acc[j] += qv.x * w0 + qv.y * w1 + qv.z * w2 + qv.w * w3;
    }
  }
#pragma unroll
  for (int j = 0; j < 8; ++j)
    qout[(m * Bb + b0 + j) * Kk + t] = acc[j];
}

// ---------------------------------------------------------------------------
// K2: u(m,b,h,k) = sum_d Wk[m,k,h*32+d] * q[m,b,h*32+d]
//     qdb(m,b,h) = sum_d q[m,b,h*32+d] * bk[m,h*32+d]
// grid (8, 8) : (m, h), 256 threads (thread = k row of Wk)
__global__ __launch_bounds__(256) void k2_uproj(
    const float* __restrict__ wk, const float* __restrict__ bk,
    const float* __restrict__ q, float* __restrict__ u,
    float* __restrict__ qdb) {
  __shared__ float qs[64 * 36];
  const int m = blockIdx.x, h = blockIdx.y, t = threadIdx.x;
#pragma unroll
  for (int p = 0; p < 8; ++p) {
    const int idx = p * 256 + t;
    const int d = idx & 31, b = idx >> 5;
    qs[b * 36 + d] = q[(m * Bb + b) * Kk + h * HD + d];
  }
  __syncthreads();
  float acc[64];
#pragma unroll
  for (int b = 0; b < 64; ++b) acc[b] = 0.f;
  const float* wrow = wk + (m * Kk + t) * Kk + h * HD;  // 32 contiguous floats
#pragma unroll
  for (int d4 = 0; d4 < 8; ++d4) {
    const float4 w4 = *(const float4*)&wrow[d4 * 4];
#pragma unroll
    for (int b = 0; b < 64; ++b) {
      const float4 q4 = *(const float4*)&qs[b * 36 + d4 * 4];
      acc[b] += q4.x * w4.x + q4.y * w4.y + q4.z * w4.z + q4.w * w4.w;
    }
  }
  for (int b = 0; b < 64; ++b)
    u[((m * Bb + b) * Hh + h) * Kk + t] = acc[b];
  if (t < 64) {
    float s = 0.f;
#pragma unroll
    for (int d = 0; d < 32; ++d)
      s += qs[t * 36 + d] * bk[m * Kk + h * HD + d];
    qdb[(m * Bb + t) * Hh + h] = s;
  }
}

// ---------------------------------------------------------------------------
// K3: raw scores(m,b,h,s) = (key(s,b,:)·u(m,b,h,:) + qdb)/sqrt(32)
// grid (64, 2, 32) : (b, mh-half of 32, s-chunk of 32), 256 threads
// thread computes 2 mh-rows {tmh, tmh+16} x 2 s {2ts, 2ts+1}
__global__ __launch_bounds__(256) void k3_scores(
    const float* __restrict__ key, const float* __restrict__ u,
    const float* __restrict__ qdb, float* __restrict__ sc) {
  __shared__ float us[32 * 260];
  __shared__ float kt[32 * 132];
  __shared__ float qd[32];
  const int b = blockIdx.x, mhh = blockIdx.y, s0 = blockIdx.z * 32,
            t = threadIdx.x;
  for (int p = 0; p < 32; ++p) {
    const int mh = mhh * 32 + p;
    us[p * 260 + t] = u[(((mh >> 3) * Bb + b) * Hh + (mh & 7)) * Kk + t];
  }
  if (t < 32) {
    const int mh = mhh * 32 + t;
    qd[t] = qdb[((mh >> 3) * Bb + b) * Hh + (mh & 7)];
  }
  float acc00 = 0.f, acc01 = 0.f, acc10 = 0.f, acc11 = 0.f;
  const int tmh = t & 15, ts = t >> 4;
  for (int kh = 0; kh < 2; ++kh) {
    __syncthreads();
#pragma unroll
    for (int p = 0; p < 16; ++p) {
      const int idx = p * 256 + t;
      const int k = idx & 127, sl = idx >> 7;
      kt[sl * 132 + k] = key[(s0 + sl) * (Bb * Kk) + b * Kk + kh * 128 + k];
    }
    __syncthreads();
#pragma unroll 8
    for (int k4 = 0; k4 < 32; ++k4) {
      const float4 u0 = *(const float4*)&us[tmh * 260 + kh * 128 + k4 * 4];
      const float4 u1 = *(const float4*)&us[(tmh + 16) * 260 + kh * 128 + k4 * 4];
      const float4 c0 = *(const float4*)&kt[(2 * ts) * 132 + k4 * 4];
      const float4 c1 = *(const float4*)&kt[(2 * ts + 1) * 132 + k4 * 4];
      acc00 += u0.x * c0.x + u0.y * c0.y + u0.z * c0.z + u0.w * c0.w;
      acc01 += u0.x * c1.x + u0.y * c1.y + u0.z * c1.z + u0.w * c1.w;
      acc10 += u1.x * c0.x + u1.y * c0.y + u1.z * c0.z + u1.w * c0.w;
      acc11 += u1.x * c1.x + u1.y * c1.y + u1.z * c1.z + u1.w * c1.w;
    }
  }
  const float scale = 0.17677669529663687f;  // 1/sqrt(32)
  const int mh0 = mhh * 32 + tmh, mh1 = mh0 + 16;
  const int r0 = ((mh0 >> 3) * Bb + b) * Hh + (mh0 & 7);
  const int r1 = ((mh1 >> 3) * Bb + b) * Hh + (mh1 & 7);
  const int s = s0 + 2 * ts;
  sc[r0 * Ss + s]     = (acc00 + qd[tmh]) * scale;
  sc[r0 * Ss + s + 1] = (acc01 + qd[tmh]) * scale;
  sc[r1 * Ss + s]     = (acc10 + qd[tmh + 16]) * scale;
  sc[r1 * Ss + s + 1] = (acc11 + qd[tmh + 16]) * scale;
}

// ---------------------------------------------------------------------------
// K3b: in-place softmax over s (per m,b,h) + attn_weights = mean over h
// grid (8, 64) : (m, b), 256 threads
__global__ __launch_bounds__(256) void k3b_softmax(float* __restrict__ sc,
                                                   float* __restrict__ out) {
  __shared__ float rows[8 * 1024];
  __shared__ float red[8];
  const int m = blockIdx.x, b = blockIdx.y, t = threadIdx.x;
  const int base = (m * Bb + b) * (Hh * Ss);
  for (int p = 0; p < 32; ++p)
    rows[p * 256 + t] = sc[base + p * 256 + t];
  __syncthreads();
  const int lane = t & 63, wid = t >> 6;
  for (int h = 0; h < 8; ++h) {
    float v0 = rows[h * 1024 + t], v1 = rows[h * 1024 + 256 + t],
          v2 = rows[h * 1024 + 512 + t], v3 = rows[h * 1024 + 768 + t];
    float mx = fmaxf(fmaxf(v0, v1), fmaxf(v2, v3));
    for (int off = 32; off > 0; off >>= 1)
      mx = fmaxf(mx, __shfl_down(mx, off, 64));
    if (lane == 0) red[wid] = mx;
    __syncthreads();
    mx = fmaxf(fmaxf(red[0], red[1]), fmaxf(red[2], red[3]));
    v0 = __expf(v0 - mx); v1 = __expf(v1 - mx);
    v2 = __expf(v2 - mx); v3 = __expf(v3 - mx);
    float sm = v0 + v1 + v2 + v3;
    for (int off = 32; off > 0; off >>= 1) sm += __shfl_down(sm, off, 64);
    if (lane == 0) red[4 + wid] = sm;
    __syncthreads();
    const float inv = 1.f / (red[4] + red[5] + red[6] + red[7]);
    v0 *= inv; v1 *= inv; v2 *= inv; v3 *= inv;
    rows[h * 1024 + t] = v0; rows[h * 1024 + 256 + t] = v1;
    rows[h * 1024 + 512 + t] = v2; rows[h * 1024 + 768 + t] = v3;
    sc[base + h * 1024 + t] = v0; sc[base + h * 1024 + 256 + t] = v1;
    sc[base + h * 1024 + 512 + t] = v2; sc[base + h * 1024 + 768 + t] = v3;
    __syncthreads();
  }
#pragma unroll
  for (int i = 0; i < 4; ++i) {
    const int s = i * 256 + t;
    float sum = 0.f;
#pragma unroll
    for (int h = 0; h < 8; ++h) sum += rows[h * 1024 + s];
    out[131072u + (m * Bb + b) * Ss + s] = sum * 0.125f;
  }
}

// ---------------------------------------------------------------------------
// K4a: partial w(m,b,h,k) = sum_{s in chunk} aw(m,b,h,s)*value(s,b,k)
// grid (64, 4, 2) : (b, s-chunk of 256, mh-half of 32), 256 threads
// thread = 4 mh rows x 8 k cols
__global__ __launch_bounds__(256) void k4a_av(const float* __restrict__ value,
                                              const float* __restrict__ aw,
                                              float* __restrict__ wpart) {
  __shared__ float aws[32 * 36];
  __shared__ float vs[32 * 260];
  const int b = blockIdx.x, sc4 = blockIdx.y, mhh = blockIdx.z,
            t = threadIdx.x;
  const int tmh = t & 7, tk = t >> 3;  // tk in 0..31
  float acc[4][8];
#pragma unroll
  for (int a = 0; a < 4; ++a)
#pragma unroll
    for (int j = 0; j < 8; ++j) acc[a][j] = 0.f;
  for (int st = 0; st < 8; ++st) {
    __syncthreads();
    const int s0 = sc4 * 256 + st * 32;
#pragma unroll
    for (int p = 0; p < 4; ++p) {
      const int idx = p * 256 + t;
      const int s = idx & 31, j = idx >> 5;
      const int mh = mhh * 32 + j;
      aws[j * 36 + s] =
          aw[(((mh >> 3) * Bb + b) * Hh + (mh & 7)) * Ss + s0 + s];
    }
#pragma unroll
    for (int p = 0; p < 32; ++p)
      vs[p * 260 + t] = value[(s0 + p) * (Bb * Kk) + b * Kk + t];
    __syncthreads();
#pragma unroll 2
    for (int s4 = 0; s4 < 8; ++s4) {
      float4 av[4];
#pragma unroll
      for (int a = 0; a < 4; ++a)
        av[a] = *(const float4*)&aws[(tmh + 8 * a) * 36 + s4 * 4];
#pragma unroll
      for (int ss = 0; ss < 4; ++ss) {
        const float4 v0 = *(const float4*)&vs[(s4 * 4 + ss) * 260 + tk * 4];
        const float4 v1 =
            *(const float4*)&vs[(s4 * 4 + ss) * 260 + 128 + tk * 4];
#pragma unroll
        for (int a = 0; a < 4; ++a) {
          const float aval = (ss == 0) ? av[a].x
                             : (ss == 1) ? av[a].y
                             : (ss == 2) ? av[a].z : av[a].w;
          acc[a][0] += aval * v0.x; acc[a][1] += aval * v0.y;
          acc[a][2] += aval * v0.z; acc[a][3] += aval * v0.w;
          acc[a][4] += aval * v1.x; acc[a][5] += aval * v1.y;
          acc[a][6] += aval * v1.z; acc[a][7] += aval * v1.w;
        }
      }
    }
  }
  float* wp = wpart + sc4 * 1048576u;
#pragma unroll
  for (int a = 0; a < 4; ++a) {
    const int mh = mhh * 32 + tmh + 8 * a;
    const int rb = (((mh >> 3) * Bb + b) * Hh + (mh & 7)) * Kk;
    float4 r0 = {acc[a][0], acc[a][1], acc[a][2], acc[a][3]};
    float4 r1 = {acc[a][4], acc[a][5], acc[a][6], acc[a][7]};
    *(float4*)&wp[rb + tk * 4] = r0;
    *(float4*)&wp[rb + 128 + tk * 4] = r1;
  }
}

// ---------------------------------------------------------------------------
// K5: w = sum of 4 partials; ctx = w @ Wv_h + bv ; attn_out = ctx @ Wo + bo ;
//     fc_in = relu(concat). grid (8, 64) : (m, b), 256 threads
__global__ __launch_bounds__(256) void k5_ctx(
    const float* __restrict__ wv, const float* __restrict__ bv,
    const float* __restrict__ wo, const float* __restrict__ bo,
    const float* __restrict__ s0in, const float* __restrict__ wpart,
    float* __restrict__ attn_out, float* __restrict__ fc) {
  __shared__ float wsh[2048];
  __shared__ float ctxs[256];
  const int m = blockIdx.x, b = blockIdx.y, t = threadIdx.x;
  const int base = (m * Bb + b) * (Hh * Kk);
#pragma unroll
  for (int p = 0; p < 8; ++p) {
    const int o = base + p * 256 + t;
    wsh[p * 256 + t] = wpart[o] + wpart[1048576u + o] + wpart[2097152u + o] +
                       wpart[3145728u + o];
  }
  __syncthreads();
  const int h = t >> 5;  // column t = h*32 + d
  float acc = bv[m * Kk + t];
  const float* wvc = wv + m * Kk * Kk + t;
  for (int k4 = 0; k4 < 64; ++k4) {
    const float4 a4 = *(const float4*)&wsh[h * 256 + k4 * 4];
    acc += a4.x * wvc[(k4 * 4 + 0) * Kk] + a4.y * wvc[(k4 * 4 + 1) * Kk] +
           a4.z * wvc[(k4 * 4 + 2) * Kk] + a4.w * wvc[(k4 * 4 + 3) * Kk];
  }
  ctxs[t] = acc;
  __syncthreads();
  float acc2 = bo[m * Kk + t];
  const float* woc = wo + m * Kk * Kk + t;
  for (int k4 = 0; k4 < 64; ++k4) {
    const float4 c4 = *(const float4*)&ctxs[k4 * 4];
    acc2 += c4.x * woc[(k4 * 4 + 0) * Kk] + c4.y * woc[(k4 * 4 + 1) * Kk] +
            c4.z * woc[(k4 * 4 + 2) * Kk] + c4.w * woc[(k4 * 4 + 3) * Kk];
  }
  const int ob = (m * Bb + b) * Kk + t;
  attn_out[ob] = acc2;
  fc[(m * Bb + b) * 512 + t] = fmaxf(acc2, 0.f);
  fc[(m * Bb + b) * 512 + 256 + t] = fmaxf(s0in[ob], 0.f);
}

// ---------------------------------------------------------------------------
// K6: h1[head] = relu(fc_in @ W1[head] + b1[head]), heads 0..3 = q,k,v,s; 4..7 = gates
// grid (8, 8, 8) : (f-tile of 128, m, head), 256 threads, 8b x 4f register tile
// LDS 25.6 KB -> higher occupancy than the 41 KB/256-block R1 version
__global__ __launch_bounds__(256) void k6_mlp1(
    const float* __restrict__ fc, const float* __restrict__ w1q,
    const float* __restrict__ w1k, const float* __restrict__ w1v,
    const float* __restrict__ w1s, const float* __restrict__ w1g,
    const float* __restrict__ b1q, const float* __restrict__ b1k,
    const float* __restrict__ b1v, const float* __restrict__ b1s,
    const float* __restrict__ b1g, float* __restrict__ h1) {
  __shared__ float At[32 * 68];   // transposed fc tile [i][b]
  __shared__ float Wt[32 * 132];  // weight tile [i][f 0..127]
  const int ft = blockIdx.x, m = blockIdx.y, head = blockIdx.z,
            t = threadIdx.x;
  const float* w1;
  const float* b1;
  if (head == 0)      { w1 = w1q; b1 = b1q; }
  else if (head == 1) { w1 = w1k; b1 = b1k; }
  else if (head == 2) { w1 = w1v; b1 = b1v; }
  else if (head == 3) { w1 = w1s; b1 = b1s; }
  else {
    w1 = w1g + (head - 4) * (Mm * 512 * Ff);
    b1 = b1g + (head - 4) * (Mm * Ff);
  }
  w1 += m * 512 * Ff;
  b1 += m * Ff;
  const int tf = t & 31, tb = t >> 5;  // thread: 8 b rows, 4 f cols
  float acc[8][4];
#pragma unroll
  for (int i = 0; i < 8; ++i)
#pragma unroll
    for (int j = 0; j < 4; ++j) acc[i][j] = 0.f;
  for (int it = 0; it < 16; ++it) {
    __syncthreads();
#pragma unroll
    for (int p = 0; p < 8; ++p) {
      const int idx = p * 256 + t;
      const int i = idx & 31, bb = idx >> 5;
      At[i * 68 + bb] = fc[(m * Bb + bb) * 512 + it * 32 + i];
    }
#pragma unroll
    for (int p = 0; p < 16; ++p) {
      const int idx = p * 256 + t;
      const int col = idx & 127, row = idx >> 7;
      Wt[row * 132 + col] = w1[(it * 32 + row) * Ff + ft * 128 + col];
    }
    __syncthreads();
#pragma unroll 4
    for (int kk = 0; kk < 32; ++kk) {
      const float4 a0 = *(const float4*)&At[kk * 68 + tb * 8];
      const float4 a1 = *(const float4*)&At[kk * 68 + tb * 8 + 4];
      const float4 w0 = *(const float4*)&Wt[kk * 132 + tf * 4];
      const float av[8] = {a0.x, a0.y, a0.z, a0.w, a1.x, a1.y, a1.z, a1.w};
#pragma unroll
      for (int i = 0; i < 8; ++i) {
        acc[i][0] += av[i] * w0.x; acc[i][1] += av[i] * w0.y;
        acc[i][2] += av[i] * w0.z; acc[i][3] += av[i] * w0.w;
      }
    }
  }
  const float4 bv0 = *(const float4*)&b1[ft * 128 + tf * 4];
  float* hb = h1 + (size_t)((head * Mm + m) * Bb) * Ff + ft * 128;
#pragma unroll
  for (int i = 0; i < 8; ++i) {
    const int bb = tb * 8 + i;
    float4 r0;
    r0.x = fmaxf(acc[i][0] + bv0.x, 0.f);
    r0.y = fmaxf(acc[i][1] + bv0.y, 0.f);
    r0.z = fmaxf(acc[i][2] + bv0.z, 0.f);
    r0.w = fmaxf(acc[i][3] + bv0.w, 0.f);
    *(float4*)&hb[bb * Ff + tf * 4] = r0;
  }
}

// ---------------------------------------------------------------------------
// K6b: gates(g,m,b) = sigmoid(h1[4+g,m,b,:] . g_w2[g,m,:] + g_b2[g,m])
// grid (32, 64) : (g*8+m, b), 64 threads
__global__ __launch_bounds__(64) void k6b_gates(
    const float* __restrict__ h1, const float* __restrict__ gw2,
    const float* __restrict__ gb2, float* __restrict__ gates) {
  const int gm = blockIdx.x, b = blockIdx.y, t = threadIdx.x;
  const int g = gm >> 3, m = gm & 7;
  const float* hrow = h1 + (size_t)(((4 + g) * Mm + m) * Bb + b) * Ff;
  const float* wrow = gw2 + (g * Mm + m) * Ff;
  float s = 0.f;
#pragma unroll
  for (int i = 0; i < 16; ++i) s += hrow[t + i * 64] * wrow[t + i * 64];
  for (int off = 32; off > 0; off >>= 1) s += __shfl_down(s, off, 64);
  if (t == 0)
    gates[(g * Mm + m) * Bb + b] =
        1.f / (1.f + __expf(-(s + gb2[g * Mm + m])));
}

// ---------------------------------------------------------------------------
// K7a: partial second-layer head outputs over an f-quarter (K=256)
// grid (16, 8, 4) : (fq*4+oc, m, head), 256 threads, 4x4 register tile
__global__ __launch_bounds__(256) void k7a_mlp2(
    const float* __restrict__ h1, const float* __restrict__ w2q,
    const float* __restrict__ w2k, const float* __restrict__ w2v,
    const float* __restrict__ w2s, float* __restrict__ hpart) {
  __shared__ float Ht[32 * 68];
  __shared__ float Wt[32 * 68];
  const int fq = blockIdx.x >> 2, oc = blockIdx.x & 3;
  const int m = blockIdx.y, head = blockIdx.z, t = threadIdx.x;
  const float* w2 =
      (head == 0) ? w2q : (head == 1) ? w2k : (head == 2) ? w2v : w2s;
  w2 += (size_t)m * Ff * Kk;
  const float* hbase = h1 + (size_t)((head * Mm + m) * Bb) * Ff + fq * 256;
  const int to = t & 15, tb = t >> 4;
  float acc[4][4];
#pragma unroll
  for (int j = 0; j < 4; ++j)
#pragma unroll
    for (int i = 0; i < 4; ++i) acc[j][i] = 0.f;
  for (int it = 0; it < 8; ++it) {
    __syncthreads();
#pragma unroll
    for (int p = 0; p < 8; ++p) {
      const int idx = p * 256 + t;
      const int f = idx & 31, bb = idx >> 5;
      Ht[f * 68 + bb] = hbase[bb * Ff + it * 32 + f];
    }
#pragma unroll
    for (int p = 0; p < 8; ++p) {
      const int idx = p * 256 + t;
      const int o = idx & 63, f = idx >> 6;
      Wt[f * 68 + o] = w2[(fq * 256 + it * 32 + f) * Kk + oc * 64 + o];
    }
    __syncthreads();
#pragma unroll 8
    for (int kk = 0; kk < 32; ++kk) {
      const float4 a4 = *(const float4*)&Ht[kk * 68 + tb * 4];
      const float4 w4 = *(const float4*)&Wt[kk * 68 + to * 4];
      acc[0][0] += a4.x * w4.x; acc[0][1] += a4.x * w4.y;
      acc[0][2] += a4.x * w4.z; acc[0][3] += a4.x * w4.w;
      acc[1][0] += a4.y * w4.x; acc[1][1] += a4.y * w4.y;
      acc[1][2] += a4.y * w4.z; acc[1][3] += a4.y * w4.w;
      acc[2][0] += a4.z * w4.x; acc[2][1] += a4.z * w4.y;
      acc[2][2] += a4.z * w4.z; acc[2][3] += a4.z * w4.w;
      acc[3][0] += a4.w * w4.x; acc[3][1] += a4.w * w4.y;
      acc[3][2] += a4.w * w4.z; acc[3][3] += a4.w * w4.w;
    }
  }
  float* hp =
      hpart + fq * 524288u + (size_t)((head * Mm + m) * Bb) * Kk + oc * 64;
#pragma unroll
  for (int j = 0; j < 4; ++j) {
    const int bb = tb * 4 + j;
    float4 r = {acc[j][0], acc[j][1], acc[j][2], acc[j][3]};
    *(float4*)&hp[bb * Kk + to * 4] = r;
  }
}

// ---------------------------------------------------------------------------
// K7b: out = gate*tanh(relu(p0+p1+p2+p3+b2)) + (1-gate)*x0, scatter to d_out
// grid 2048, 256 threads
__global__ __launch_bounds__(256) void k7b_final(
    const float* __restrict__ hpart, const float* __restrict__ gates,
    const float* __restrict__ b2q, const float* __restrict__ b2k,
    const float* __restrict__ b2v, const float* __restrict__ b2s,
    const float* __restrict__ q0, const float* __restrict__ k0,
    const float* __restrict__ v0, const float* __restrict__ s0,
    float* __restrict__ out) {
  const int idx = blockIdx.x * 256 + threadIdx.x;  // 0..524287
  const int o = idx & 255;
  const int b = (idx >> 8) & 63;
  const int m = (idx >> 14) & 7;
  const int head = idx >> 17;
  const float* b2 = (head == 0) ? b2q : (head == 1) ? b2k
                    : (head == 2) ? b2v : b2s;
  const float* x0 = (head == 0) ? q0 : (head == 1) ? k0
                    : (head == 2) ? v0 : s0;
  const unsigned ooff = (head == 0) ? 786432u
                        : (head == 1) ? 917504u
                        : (head == 2) ? 1048576u : 655360u;
  float v = hpart[idx] + hpart[524288u + idx] + hpart[1048576u + idx] +
            hpart[1572864u + idx] + b2[m * Kk + o];
  v = tanhf(fmaxf(v, 0.f));
  const float g = gates[(head * Mm + m) * Bb + b];
  const float x = x0[(m * Bb + b) * Kk + o];
  out[ooff + (m * Bb + b) * Kk + o] = g * v + (1.f - g) * x;
}

// ---------------------------------------------------------------------------
extern "C" void kernel_launch(void* const* d_in, const int* in_sizes, int n_in,
                              void* d_out, int out_size, void* d_ws,
                              size_t ws_size, hipStream_t stream) {
  (void)in_sizes; (void)n_in; (void)out_size; (void)ws_size;
  const float* s0  = (const float*)d_in[0];
  const float* q0  = (const float*)d_in[1];
  const float* k0  = (const float*)d_in[2];
  const float* v0  = (const float*)d_in[3];
  const float* key = (const float*)d_in[4];
  const float* val = (const float*)d_in[5];
  const float* wq  = (const float*)d_in[6];
  const float* wk  = (const float*)d_in[7];
  const float* wv  = (const float*)d_in[8];
  const float* bqa = (const float*)d_in[9];
  const float* bka = (const float*)d_in[10];
  const float* bva = (const float*)d_in[11];
  const float* wo  = (const float*)d_in[12];
  const float* bo  = (const float*)d_in[13];
  const float* qw1 = (const float*)d_in[14];
  const float* qb1 = (const float*)d_in[15];
  const float* qw2 = (const float*)d_in[16];
  const float* qb2 = (const float*)d_in[17];
  const float* kw1 = (const float*)d_in[18];
  const float* kb1 = (const float*)d_in[19];
  const float* kw2 = (const float*)d_in[20];
  const float* kb2 = (const float*)d_in[21];
  const float* vw1 = (const float*)d_in[22];
  const float* vb1 = (const float*)d_in[23];
  const float* vw2 = (const float*)d_in[24];
  const float* vb2 = (const float*)d_in[25];
  const float* sw1 = (const float*)d_in[26];
  const float* sb1 = (const float*)d_in[27];
  const float* sw2 = (const float*)d_in[28];
  const float* sb2 = (const float*)d_in[29];
  const float* gw1 = (const float*)d_in[30];
  const float* gb1 = (const float*)d_in[31];
  const float* gw2 = (const float*)d_in[32];
  const float* gb2 = (const float*)d_in[33];
  float* ws  = (float*)d_ws;
  float* out = (float*)d_out;

  k1_qproj<<<dim3(8, 8), 256, 0, stream>>>(q0, wq, bqa, ws + WS_Q);
  k2_uproj<<<dim3(8, 8), 256, 0, stream>>>(wk, bka, ws + WS_Q, ws + WS_U,
                                           ws + WS_QDB);
  k3_scores<<<dim3(64, 2, 32), 256, 0, stream>>>(key, ws + WS_U, ws + WS_QDB,
                                                 ws + WS_SC);
  k3b_softmax<<<dim3(8, 64), 256, 0, stream>>>(ws + WS_SC, out);
  k4a_av<<<dim3(64, 4, 2), 256, 0, stream>>>(val, ws + WS_SC, ws + WS_WPART);
  k5_ctx<<<dim3(8, 64), 256, 0, stream>>>(wv, bva, wo, bo, s0, ws + WS_WPART,
                                          out, ws + WS_FC);
  k6_mlp1<<<dim3(8, 8, 8), 256, 0, stream>>>(ws + WS_FC, qw1, kw1, vw1, sw1,
                                             gw1, qb1, kb1, vb1, sb1, gb1,
                                             ws + WS_H1);
  k6b_gates<<<dim3(32, 64), 64, 0, stream>>>(ws + WS_H1, gw2, gb2,
                                             ws + WS_GATES);
  k7a_mlp2<<<dim3(16, 8, 4), 256, 0, stream>>>(ws + WS_H1, qw2, kw2, vw2, sw2,
                                               ws + WS_HPART);
  k7b_final<<<dim3(2048), 256, 0, stream>>>(ws + WS_HPART, ws + WS_GATES, qb2,
                                            kb2, vb2, sb2, q0, k0, v0, s0,
                                            out);
}